// Round 1
// 15481.862 us; speedup vs baseline: 1.1163x; 1.1163x over previous
//
#include <hip/hip_runtime.h>
#include <hip/hip_bf16.h>

#define B 512
#define S 64
#define H 1024
#define O 1024
#define T 128
#define ATT 64

typedef __bf16 bf16;
typedef __bf16 bf16x8 __attribute__((ext_vector_type(8)));
typedef __bf16 bf16x4 __attribute__((ext_vector_type(4)));
typedef float f32x4 __attribute__((ext_vector_type(4)));

static __device__ __forceinline__ float bf2f(bf16 b) {
    unsigned short s = __builtin_bit_cast(unsigned short, b);
    unsigned int u = ((unsigned int)s) << 16;
    return __builtin_bit_cast(float, u);
}
static __device__ __forceinline__ bf16 f2bf(float f) {
    unsigned int u = __builtin_bit_cast(unsigned int, f);
    unsigned int r = (u + 0x7fffu + ((u >> 16) & 1u)) >> 16;
    return __builtin_bit_cast(bf16, (unsigned short)r);
}

// ---------------------------------------------------------------------------
// Generic bf16 MFMA GEMM:  C[M,N] = act(A @ W^T + bias)
// Two K-segments (A0: k<SPLITK, A1: k>=SPLITK), loop starts at KSTART.
// W is [N, K] row-major. Block 256 thr = 4 waves (2x2); tile 32M x 64N.
// grid = (N/64, M/32). All K bounds compile-time -> fully unrollable.
// ---------------------------------------------------------------------------
template <bool RELU, int K, int SPLITK, int KSTART>
__global__ __launch_bounds__(256) void gemm_kernel(
    const bf16* __restrict__ A0, long lda0,
    const bf16* __restrict__ A1, long lda1,
    const bf16* __restrict__ W, const float* __restrict__ bias,
    float* __restrict__ Cf, long ldc, bf16* __restrict__ Cbf, int ldcbf) {
    const int tid = threadIdx.x;
    const int wave = tid >> 6, lane = tid & 63;
    const int wm = wave >> 1, wn = wave & 1;
    const int quad = lane >> 4, r = lane & 15;
    const int kq = quad * 8;

    const int m0 = blockIdx.y * 32 + wm * 16 + r;
    const int n0 = blockIdx.x * 64 + wn * 32;

    const bf16* a0row = A0 + (long)m0 * lda0;
    const bf16* a1row = A1 + (long)m0 * lda1;
    const bf16* w0 = W + (long)(n0 + r) * K;
    const bf16* w1 = W + (long)(n0 + 16 + r) * K;

    f32x4 acc0 = {0.f, 0.f, 0.f, 0.f}, acc1 = {0.f, 0.f, 0.f, 0.f};

    for (int k0 = KSTART; k0 < K; k0 += 32) {
        bf16x8 av;
        if (k0 < SPLITK)
            av = *(const bf16x8*)(a0row + k0 + kq);
        else
            av = *(const bf16x8*)(a1row + (k0 - SPLITK) + kq);
        bf16x8 bv0 = *(const bf16x8*)(w0 + k0 + kq);
        bf16x8 bv1 = *(const bf16x8*)(w1 + k0 + kq);
        acc0 = __builtin_amdgcn_mfma_f32_16x16x32_bf16(av, bv0, acc0, 0, 0, 0);
        acc1 = __builtin_amdgcn_mfma_f32_16x16x32_bf16(av, bv1, acc1, 0, 0, 0);
    }

    // D layout: col = lane&15, row = quad*4 + reg  (m89/m91-verified)
    const int mbase = blockIdx.y * 32 + wm * 16 + quad * 4;
    const int nA = n0 + r, nB = n0 + 16 + r;
    const float biasA = bias[nA], biasB = bias[nB];
#pragma unroll
    for (int reg = 0; reg < 4; ++reg) {
        const int m = mbase + reg;
        float vA = acc0[reg] + biasA;
        float vB = acc1[reg] + biasB;
        if (RELU) { vA = fmaxf(vA, 0.f); vB = fmaxf(vB, 0.f); }
        if (Cf) {
            Cf[(long)m * ldc + nA] = vA;
            Cf[(long)m * ldc + nB] = vB;
        }
        if (Cbf) {
            Cbf[(long)m * ldcbf + nA] = f2bf(vA);
            Cbf[(long)m * ldcbf + nB] = f2bf(vB);
        }
    }
}

// ---------------------------------------------------------------------------
// Batched fc_out over the whole h history: rows m = t*B + b of Hh[T*B, H],
// out[b, t, n] = Hh[m] @ Wo^T + bo.  grid = (16, T*B/32).
// ---------------------------------------------------------------------------
__global__ __launch_bounds__(256) void fcout_batch_kernel(
    const bf16* __restrict__ Hh, const bf16* __restrict__ Wo,
    const float* __restrict__ bo, float* __restrict__ out) {
    const int tid = threadIdx.x;
    const int wave = tid >> 6, lane = tid & 63;
    const int wm = wave >> 1, wn = wave & 1;
    const int quad = lane >> 4, r = lane & 15;
    const int kq = quad * 8;

    const int m0 = blockIdx.y * 32 + wm * 16 + r;
    const int n0 = blockIdx.x * 64 + wn * 32;

    const bf16* arow = Hh + (long)m0 * H;
    const bf16* w0 = Wo + (long)(n0 + r) * H;
    const bf16* w1 = Wo + (long)(n0 + 16 + r) * H;

    f32x4 acc0 = {0.f, 0.f, 0.f, 0.f}, acc1 = {0.f, 0.f, 0.f, 0.f};
    for (int k0 = 0; k0 < H; k0 += 32) {
        bf16x8 av = *(const bf16x8*)(arow + k0 + kq);
        bf16x8 bv0 = *(const bf16x8*)(w0 + k0 + kq);
        bf16x8 bv1 = *(const bf16x8*)(w1 + k0 + kq);
        acc0 = __builtin_amdgcn_mfma_f32_16x16x32_bf16(av, bv0, acc0, 0, 0, 0);
        acc1 = __builtin_amdgcn_mfma_f32_16x16x32_bf16(av, bv1, acc1, 0, 0, 0);
    }

    const int mbase = blockIdx.y * 32 + wm * 16 + quad * 4;
    const int nA = n0 + r, nB = n0 + 16 + r;
    const float biasA = bo[nA], biasB = bo[nB];
#pragma unroll
    for (int reg = 0; reg < 4; ++reg) {
        const int m = mbase + reg;
        const int b = m & (B - 1);
        const int tt = m >> 9;  // B = 512
        float* orow = out + (long)b * ((long)T * O) + (long)tt * O;
        orow[nA] = acc0[reg] + biasA;
        orow[nB] = acc1[reg] + biasB;
    }
}

// ---------------------------------------------------------------------------
// Attention logits (fused weights, K=1024) + softmax.
// logits = h @ Wlog^T + bvec  -> softmax rows -> attn_w.  grid = (1, B/32).
// ---------------------------------------------------------------------------
__global__ __launch_bounds__(256) void attn_logits_kernel(
    const bf16* __restrict__ h, const bf16* __restrict__ Wlog,
    const float* __restrict__ bvec, bf16* __restrict__ attn_w) {
    __shared__ float lg[32][64];
    const int tid = threadIdx.x;
    const int wave = tid >> 6, lane = tid & 63;
    const int wm = wave >> 1, wn = wave & 1;
    const int quad = lane >> 4, r = lane & 15;
    const int kq = quad * 8;

    const int m0 = blockIdx.y * 32 + wm * 16 + r;
    const int n0 = wn * 32;

    const bf16* hrow = h + (long)m0 * H;
    const bf16* w0 = Wlog + (long)(n0 + r) * H;
    const bf16* w1 = Wlog + (long)(n0 + 16 + r) * H;

    f32x4 acc0 = {0.f, 0.f, 0.f, 0.f}, acc1 = {0.f, 0.f, 0.f, 0.f};
    for (int k0 = 0; k0 < H; k0 += 32) {
        bf16x8 av = *(const bf16x8*)(hrow + k0 + kq);
        bf16x8 bv0 = *(const bf16x8*)(w0 + k0 + kq);
        bf16x8 bv1 = *(const bf16x8*)(w1 + k0 + kq);
        acc0 = __builtin_amdgcn_mfma_f32_16x16x32_bf16(av, bv0, acc0, 0, 0, 0);
        acc1 = __builtin_amdgcn_mfma_f32_16x16x32_bf16(av, bv1, acc1, 0, 0, 0);
    }

    const int mloc = wm * 16 + quad * 4;
#pragma unroll
    for (int reg = 0; reg < 4; ++reg) {
        lg[mloc + reg][n0 + r] = acc0[reg] + bvec[n0 + r];
        lg[mloc + reg][n0 + 16 + r] = acc1[reg] + bvec[n0 + 16 + r];
    }
    __syncthreads();

    if (tid < 32) {
        const int row = tid;
        float mx = -1e30f;
#pragma unroll
        for (int s = 0; s < 64; ++s) mx = fmaxf(mx, lg[row][s]);
        float sum = 0.f;
#pragma unroll
        for (int s = 0; s < 64; ++s) sum += __expf(lg[row][s] - mx);
        const float inv = 1.f / sum;
        const long gb = (long)(blockIdx.y * 32 + row) * 64;
#pragma unroll
        for (int s = 0; s < 64; ++s)
            attn_w[gb + s] = f2bf(__expf(lg[row][s] - mx) * inv);
    }
}

// ---------------------------------------------------------------------------
// attn_applied[b,d] = sum_s w[b,s] * enc[b,s,d].  One block per batch row.
// 256 threads x bf16x4 (8 B/lane), non-temporal enc loads (don't thrash L2).
// grid = B.
// ---------------------------------------------------------------------------
__global__ __launch_bounds__(256) void attn_apply_kernel(
    const bf16* __restrict__ attn_w, const bf16* __restrict__ enc,
    bf16* __restrict__ attn_out) {
    __shared__ float w[64];
    const int b = blockIdx.x;
    const int tid = threadIdx.x;
    if (tid < 64) w[tid] = bf2f(attn_w[b * 64 + tid]);
    __syncthreads();
    const bf16* e = enc + (long)b * (S * 1024) + tid * 4;
    float a0 = 0.f, a1 = 0.f, a2 = 0.f, a3 = 0.f;
#pragma unroll 16
    for (int s = 0; s < S; ++s) {
        unsigned long long raw =
            __builtin_nontemporal_load((const unsigned long long*)(e + (long)s * 1024));
        bf16x4 v = __builtin_bit_cast(bf16x4, raw);
        const float ws = w[s];
        a0 += ws * bf2f(v[0]);
        a1 += ws * bf2f(v[1]);
        a2 += ws * bf2f(v[2]);
        a3 += ws * bf2f(v[3]);
    }
    bf16x4 o = {f2bf(a0), f2bf(a1), f2bf(a2), f2bf(a3)};
    *(bf16x4*)(attn_out + (long)b * 1024 + tid * 4) = o;
}

// ---------------------------------------------------------------------------
// Fused GRU: 6 simultaneous GEMM accumulations + gates + h_new writeback.
// grid = (H/64, B/32).
// ---------------------------------------------------------------------------
__global__ __launch_bounds__(256) void gru_kernel(
    const bf16* __restrict__ gin, const bf16* __restrict__ hbf,
    const bf16* __restrict__ Wih, const bf16* __restrict__ Whh,
    const float* __restrict__ bih, const float* __restrict__ bhh,
    const float* __restrict__ hold, float* __restrict__ hnew,
    bf16* __restrict__ hnewbf) {
    const int tid = threadIdx.x;
    const int wave = tid >> 6, lane = tid & 63;
    const int wm = wave >> 1, wn = wave & 1;
    const int quad = lane >> 4, r = lane & 15;
    const int kq = quad * 8;

    const int m0 = blockIdx.y * 32 + wm * 16 + r;
    const int n0 = blockIdx.x * 64 + wn * 32;

    const bf16* grow = gin + (long)m0 * H;
    const bf16* hrow = hbf + (long)m0 * H;

    const bf16* wi[3][2];
    const bf16* wh[3][2];
#pragma unroll
    for (int g = 0; g < 3; ++g) {
#pragma unroll
        for (int ni = 0; ni < 2; ++ni) {
            const long row = (long)g * H + n0 + ni * 16 + r;
            wi[g][ni] = Wih + row * H;
            wh[g][ni] = Whh + row * H;
        }
    }

    f32x4 aI[3][2], aH[3][2];
#pragma unroll
    for (int g = 0; g < 3; ++g)
#pragma unroll
        for (int ni = 0; ni < 2; ++ni) {
            aI[g][ni] = (f32x4){0.f, 0.f, 0.f, 0.f};
            aH[g][ni] = (f32x4){0.f, 0.f, 0.f, 0.f};
        }

    for (int k0 = 0; k0 < H; k0 += 32) {
        const int ko = k0 + kq;
        bf16x8 ai = *(const bf16x8*)(grow + ko);
        bf16x8 ah = *(const bf16x8*)(hrow + ko);
#pragma unroll
        for (int g = 0; g < 3; ++g) {
#pragma unroll
            for (int ni = 0; ni < 2; ++ni) {
                bf16x8 bi = *(const bf16x8*)(wi[g][ni] + ko);
                aI[g][ni] = __builtin_amdgcn_mfma_f32_16x16x32_bf16(ai, bi, aI[g][ni], 0, 0, 0);
                bf16x8 bh = *(const bf16x8*)(wh[g][ni] + ko);
                aH[g][ni] = __builtin_amdgcn_mfma_f32_16x16x32_bf16(ah, bh, aH[g][ni], 0, 0, 0);
            }
        }
    }

    const int mbase = blockIdx.y * 32 + wm * 16 + quad * 4;
#pragma unroll
    for (int ni = 0; ni < 2; ++ni) {
        const int j = n0 + ni * 16 + r;
        const float bir = bih[j], biz = bih[j + H], bin = bih[j + 2 * H];
        const float bhr = bhh[j], bhz = bhh[j + H], bhn = bhh[j + 2 * H];
#pragma unroll
        for (int reg = 0; reg < 4; ++reg) {
            const int m = mbase + reg;
            const float gir = aI[0][ni][reg] + bir, ghr = aH[0][ni][reg] + bhr;
            const float giz = aI[1][ni][reg] + biz, ghz = aH[1][ni][reg] + bhz;
            const float ginv = aI[2][ni][reg] + bin, ghn = aH[2][ni][reg] + bhn;
            const float rg = 1.f / (1.f + __expf(-(gir + ghr)));
            const float zg = 1.f / (1.f + __expf(-(giz + ghz)));
            const float ng = tanhf(ginv + rg * ghn);
            const long idx = (long)m * H + j;
            const float hv = hold[idx];
            const float hnv = (1.f - zg) * ng + zg * hv;
            hnew[idx] = hnv;
            hnewbf[idx] = f2bf(hnv);
        }
    }
}

// ---------------------------------------------------------------------------
// init / precompute kernels
// ---------------------------------------------------------------------------
// dst[r*ld_dst + doff + c] = bf16(src[r*ld_src + soff + c]), c in [0, cols4*4)
__global__ __launch_bounds__(256) void cast2d_kernel(
    const float* __restrict__ src, long ld_src, long soff,
    bf16* __restrict__ dst, long ld_dst, long doff, long rows, long cols4) {
    const long total = rows * cols4;
    const long stride = (long)gridDim.x * blockDim.x;
    for (long i = (long)blockIdx.x * blockDim.x + threadIdx.x; i < total; i += stride) {
        const long rr = i / cols4;
        const long c = (i - rr * cols4) << 2;
        const float4 v = *(const float4*)(src + rr * ld_src + soff + c);
        bf16x4 o = {f2bf(v.x), f2bf(v.y), f2bf(v.z), f2bf(v.w)};
        *(bf16x4*)(dst + rr * ld_dst + doff + c) = o;
    }
}

// dst[k*n + j] = bf16(src[j*n + k])  (transpose + cast), n x n, n % 32 == 0
__global__ __launch_bounds__(256) void transpose_cast_kernel(
    const float* __restrict__ src, bf16* __restrict__ dst, int n) {
    __shared__ float tile[32][33];
    const int tx = threadIdx.x & 31, ty = threadIdx.x >> 5;  // ty in [0,8)
    const int x0 = blockIdx.x * 32, y0 = blockIdx.y * 32;
#pragma unroll
    for (int i = 0; i < 32; i += 8)
        tile[ty + i][tx] = src[(long)(y0 + ty + i) * n + x0 + tx];
    __syncthreads();
#pragma unroll
    for (int i = 0; i < 32; i += 8)
        dst[(long)(x0 + ty + i) * n + y0 + tx] = f2bf(tile[tx][ty + i]);
}

// Wlog1[i] = bf16(P1[i] + Wa[r*2048 + 1024 + c]),  i = r*1024 + c, 64x1024
__global__ __launch_bounds__(256) void addcast_wlog_kernel(
    const float* __restrict__ P1, const float* __restrict__ Wa,
    bf16* __restrict__ Wlog1) {
    const int i = blockIdx.x * 256 + threadIdx.x;
    if (i < 64 * 1024) {
        const int rr = i >> 10, c = i & 1023;
        Wlog1[i] = f2bf(P1[i] + Wa[(long)rr * 2048 + 1024 + c]);
    }
}

// b_out[r] = b_in[r] + sum_j W[r*ld + j] * v[j], j in [0,1024). grid = rows.
__global__ __launch_bounds__(256) void bias_fuse_kernel(
    const float* __restrict__ W, long ld, const float* __restrict__ v,
    const float* __restrict__ b_in, float* __restrict__ b_out) {
    __shared__ float red[256];
    const int r = blockIdx.x, tid = threadIdx.x;
    float s = 0.f;
    for (int j = tid; j < 1024; j += 256) s += W[(long)r * ld + j] * v[j];
    red[tid] = s;
    __syncthreads();
    for (int off = 128; off > 0; off >>= 1) {
        if (tid < off) red[tid] += red[tid + off];
        __syncthreads();
    }
    if (tid == 0) b_out[r] = b_in[r] + red[0];
}

__global__ __launch_bounds__(256) void init_h_kernel(
    const float* __restrict__ h0, float* __restrict__ hfp,
    bf16* __restrict__ hbf, long n4) {
    long i = (long)blockIdx.x * blockDim.x + threadIdx.x;
    const long stride = (long)gridDim.x * blockDim.x;
    for (; i < n4; i += stride) {
        float4 v = ((const float4*)h0)[i];
        ((float4*)hfp)[i] = v;
        bf16x4 o = {f2bf(v.x), f2bf(v.y), f2bf(v.z), f2bf(v.w)};
        *(bf16x4*)(hbf + 4 * i) = o;
    }
}

__global__ __launch_bounds__(256) void copy_f32_kernel(
    const float* __restrict__ src, float* __restrict__ dst, long n4) {
    long i = (long)blockIdx.x * blockDim.x + threadIdx.x;
    const long stride = (long)gridDim.x * blockDim.x;
    for (; i < n4; i += stride) ((float4*)dst)[i] = ((const float4*)src)[i];
}

// ---------------------------------------------------------------------------
extern "C" void kernel_launch(void* const* d_in, const int* in_sizes, int n_in,
                              void* d_out, int out_size, void* d_ws, size_t ws_size,
                              hipStream_t stream) {
    const float* enc_f = (const float*)d_in[0];
    const float* hidden = (const float*)d_in[1];
    // d_in[2] = max_length (always 128 here)
    const float* Wa = (const float*)d_in[3];
    const float* ba = (const float*)d_in[4];
    const float* Wc = (const float*)d_in[5];
    const float* bc = (const float*)d_in[6];
    const float* Wih = (const float*)d_in[7];
    const float* Whh = (const float*)d_in[8];
    const float* bih = (const float*)d_in[9];
    const float* bhh = (const float*)d_in[10];
    const float* Wo = (const float*)d_in[11];
    const float* bo = (const float*)d_in[12];
    float* out = (float*)d_out;

    // ---- workspace carve-up ----
    char* p = (char*)d_ws;
    auto carve = [&](long bytes) {
        char* q = p;
        p += (bytes + 255) & ~255L;
        return q;
    };
    bf16* Wlog0 = (bf16*)carve((long)64 * 1024 * 2);        // Wa_h (t=0 logits)
    bf16* Wlog1 = (bf16*)carve((long)64 * 1024 * 2);        // Wa_d@Wo + Wa_h
    bf16* Wcomb = (bf16*)carve((long)H * 2048 * 2);         // [Wc_d@Wo | Wc_a]
    bf16* Wih_bf = (bf16*)carve((long)3 * H * H * 2);
    bf16* Whh_bf = (bf16*)carve((long)3 * H * H * 2);
    bf16* Wo_bf = (bf16*)carve((long)O * H * 2);
    bf16* enc_bf = (bf16*)carve((long)B * S * 1024 * 2);    // also init scratch
    bf16* attn_bf = (bf16*)carve((long)B * 1024 * 2);
    bf16* gru_bf = (bf16*)carve((long)B * H * 2);
    bf16* attn_w = (bf16*)carve((long)B * 64 * 2);
    bf16* h0bf = (bf16*)carve((long)B * H * 2);
    bf16* hbfA = (bf16*)carve((long)B * H * 2);             // fallback h slots
    bf16* hbfB = (bf16*)carve((long)B * H * 2);
    float* hfpA = (float*)carve((long)B * H * 4);
    float* hfpB = (float*)carve((long)B * H * 4);
    float* blog1 = (float*)carve(64 * 4);
    float* bc2 = (float*)carve((long)H * 4);
    float* zeros = (float*)carve(1024 * 4);

    const long persistent = (long)(p - (char*)d_ws);
    const long histBytes = (long)T * B * H * 2;  // 128 MB bf16 h history
    const bool batched = (ws_size >= (size_t)(persistent + histBytes + 256));
    bf16* hist = batched ? (bf16*)carve(histBytes) : nullptr;
    auto slot = [&](int t2) -> bf16* {
        return batched ? hist + (long)t2 * ((long)B * H)
                       : ((t2 & 1) ? hbfB : hbfA);
    };

    // ---- init-time scratch aliased into enc_bf (consumed before enc cast) ----
    {
        char* sp = (char*)enc_bf;
        auto scarve = [&](long bytes) {
            char* q = sp;
            sp += (bytes + 255) & ~255L;
            return q;
        };
        bf16* Wad = (bf16*)scarve((long)64 * 1024 * 2);
        bf16* Wcd = (bf16*)scarve((long)H * 1024 * 2);
        bf16* WoT = (bf16*)scarve((long)H * O * 2);
        float* P1 = (float*)scarve((long)64 * 1024 * 4);
        float* P2 = (float*)scarve((long)H * 1024 * 4);

        hipMemsetAsync(zeros, 0, 1024 * 4, stream);

        auto cast2d = [&](const float* src, long lds_, long so, bf16* dst,
                          long ldd, long doff, long rows, long cols) {
            long n4 = rows * (cols / 4);
            int blocks = (int)((n4 + 255) / 256);
            if (blocks > 4096) blocks = 4096;
            cast2d_kernel<<<blocks, 256, 0, stream>>>(src, lds_, so, dst, ldd,
                                                      doff, rows, cols / 4);
        };
        // plain casts
        cast2d(Wa, 2048, 1024, Wlog0, 1024, 0, 64, 1024);       // Wa_h
        cast2d(Wa, 2048, 0, Wad, 1024, 0, 64, 1024);            // Wa_d
        cast2d(Wc, 2048, 0, Wcd, 1024, 0, 1024, 1024);          // Wc_d
        cast2d(Wc, 2048, 1024, Wcomb, 2048, 1024, 1024, 1024);  // Wc_a half
        cast2d(Wih, 1024, 0, Wih_bf, 1024, 0, 3 * H, 1024);
        cast2d(Whh, 1024, 0, Whh_bf, 1024, 0, 3 * H, 1024);
        cast2d(Wo, 1024, 0, Wo_bf, 1024, 0, O, 1024);
        transpose_cast_kernel<<<dim3(32, 32), 256, 0, stream>>>(Wo, WoT, 1024);

        // P1 = Wa_d @ Wo  (via WoT as [N,K]);  P2 = Wc_d @ Wo
        gemm_kernel<false, 1024, 1024, 0><<<dim3(16, 2), 256, 0, stream>>>(
            Wad, 1024, Wad, 1024, WoT, zeros, P1, 1024, nullptr, 0);
        gemm_kernel<false, 1024, 1024, 0><<<dim3(16, 32), 256, 0, stream>>>(
            Wcd, 1024, Wcd, 1024, WoT, zeros, P2, 1024, nullptr, 0);

        addcast_wlog_kernel<<<256, 256, 0, stream>>>(P1, Wa, Wlog1);
        cast2d(P2, 1024, 0, Wcomb, 2048, 0, 1024, 1024);        // Wxc half

        bias_fuse_kernel<<<64, 256, 0, stream>>>(Wa, 2048, bo, ba, blog1);
        bias_fuse_kernel<<<1024, 256, 0, stream>>>(Wc, 2048, bo, bc, bc2);

        // scratch consumed -> now cast enc over it
        cast2d(enc_f, 1024, 0, enc_bf, 1024, 0, (long)B * S, 1024);
        init_h_kernel<<<512, 256, 0, stream>>>(hidden, hfpA, h0bf, (long)B * H / 4);
    }

    const dim3 blk(256);
    const dim3 grid_nm(H / 64, B / 32);  // (16,16)
    const dim3 grid_attn(1, B / 32);     // (1,16)

    for (int t = 0; t < T; ++t) {
        const bf16* h_in = (t == 0) ? h0bf : slot(t - 1);
        bf16* h_out = slot(t);
        const float* hfp_r = (t & 1) ? hfpB : hfpA;
        float* hfp_w = (t & 1) ? hfpA : hfpB;

        // 1) attention logits (K=1024, Wo folded in for t>=1) + softmax
        attn_logits_kernel<<<grid_attn, blk, 0, stream>>>(
            h_in, t ? Wlog1 : Wlog0, t ? blog1 : ba, attn_w);
        // 2) attention apply (vectorized, non-temporal enc stream)
        attn_apply_kernel<<<B, blk, 0, stream>>>(attn_w, enc_bf, attn_bf);
        // 3) combine + relu -> gru_in.  t=0: dec==0, skip h-segment, orig bias.
        if (t == 0)
            gemm_kernel<true, 2048, 1024, 1024><<<grid_nm, blk, 0, stream>>>(
                h_in, 1024, attn_bf, 1024, Wcomb, bc, nullptr, 0, gru_bf, H);
        else
            gemm_kernel<true, 2048, 1024, 0><<<grid_nm, blk, 0, stream>>>(
                h_in, 1024, attn_bf, 1024, Wcomb, bc2, nullptr, 0, gru_bf, H);
        // 4) fused GRU -> h_new (fp32 ping-pong + bf16 history slot)
        gru_kernel<<<grid_nm, blk, 0, stream>>>(
            gru_bf, h_in, Wih_bf, Whh_bf, bih, bhh, hfp_r, hfp_w, h_out);
        // 5) fc_out only if we cannot batch it (workspace too small)
        if (!batched)
            gemm_kernel<false, 1024, 1024, 0><<<grid_nm, blk, 0, stream>>>(
                h_out, 1024, h_out, 1024, Wo_bf, bo,
                out + (long)t * O, (long)T * O, nullptr, 0);
    }

    // batched fc_out over the whole history: one big GEMM off the critical path
    if (batched)
        fcout_batch_kernel<<<dim3(16, (T * B) / 32), blk, 0, stream>>>(
            hist, Wo_bf, bo, out);

    // final hidden (t=127 wrote hfpA) -> tail of d_out
    copy_f32_kernel<<<512, 256, 0, stream>>>(hfpA, out + (long)B * T * O,
                                             (long)B * H / 4);
}